// Round 5
// baseline (250.156 us; speedup 1.0000x reference)
//
#include <hip/hip_runtime.h>
#include <hip/hip_bf16.h>
#include <math.h>

#define Hdim 768
#define Idim 3072
#define Tn   1024
#define En   8
#define LDB  136   // Bs stride (shorts): 272 B ≡ 4 banks (mod 32)

using v4f     = __attribute__((ext_vector_type(4))) float;
using short8  = __attribute__((ext_vector_type(8))) short;
using short4v = __attribute__((ext_vector_type(4))) short;

__device__ inline unsigned short f2bf(float f) {
    unsigned u = __float_as_uint(f);
    u += 0x7fffu + ((u >> 16) & 1u);   // RNE
    return (unsigned short)(u >> 16);
}
__device__ inline short4v pack4(float4 v) {
    return short4v{ (short)f2bf(v.x), (short)f2bf(v.y), (short)f2bf(v.z), (short)f2bf(v.w) };
}
__device__ __forceinline__ void gl2lds16(const unsigned short* g, unsigned short* l) {
    __builtin_amdgcn_global_load_lds(
        (const __attribute__((address_space(1))) void*)g,
        (__attribute__((address_space(3))) void*)l, 16, 0, 0);
}

// ---------------- gate ----------------
__global__ __launch_bounds__(256) void gate_kernel(
    const float* __restrict__ x, const float* __restrict__ gw, const float* __restrict__ gb,
    float* __restrict__ gsum, float* __restrict__ gsumsq,
    int* __restrict__ count, int* __restrict__ sel)
{
    __shared__ float gws[8 * 772];
    __shared__ float lg[8][8];
    int tid = threadIdx.x;
    long t0 = (long)blockIdx.x * 8;
    for (int i = tid; i < 8 * 768; i += 256) gws[(i / 768) * 772 + (i % 768)] = gw[i];
    __syncthreads();

    int tok = tid >> 5, e = (tid >> 2) & 7, qr = tid & 3;
    const float4* xp = (const float4*)(x + (t0 + tok) * Hdim) + qr * 48;
    const float4* gp = (const float4*)(gws + e * 772) + qr * 48;
    float a0 = 0.f, a1 = 0.f;
#pragma unroll 8
    for (int i = 0; i < 48; i += 2) {
        float4 xa = xp[i], ga = gp[i], xc = xp[i + 1], gc = gp[i + 1];
        a0 += xa.x * ga.x + xa.y * ga.y + xa.z * ga.z + xa.w * ga.w;
        a1 += xc.x * gc.x + xc.y * gc.y + xc.z * gc.z + xc.w * gc.w;
    }
    float acc = a0 + a1;
    acc += __shfl_xor(acc, 1);
    acc += __shfl_xor(acc, 2);
    if (qr == 0) lg[tok][e] = acc + gb[e];
    __syncthreads();

    if (tid < 8) {
        float best = lg[tid][0]; int bi = 0;
        for (int j = 1; j < 8; j++) { float v = lg[tid][j]; if (v > best) { best = v; bi = j; } }
        sel[t0 + tid] = bi;
        atomicAdd(&count[bi], 1);
    } else if (tid < 16) {
        int e2 = tid - 8;
        float s = 0.f, ss = 0.f;
        for (int t2 = 0; t2 < 8; t2++) { float v = lg[t2][e2]; s += v; ss += v * v; }
        atomicAdd(&gsum[e2], s);
        atomicAdd(&gsumsq[e2], ss);
    }
}

// ---------------- finalize + scatter (single block) ----------------
__global__ __launch_bounds__(1024) void finscat_kernel(
    const float* __restrict__ gsum, const float* __restrict__ gsumsq,
    const int* __restrict__ count, int* __restrict__ offsets,
    const int* __restrict__ sel, int* __restrict__ perm,
    float* __restrict__ out_lb)
{
    __shared__ int lcur[8];
    int tid = threadIdx.x;
    if (tid == 0) {
        float accr = 0.f;
        for (int e = 0; e < 8; e++) {
            float mean = gsum[e] * (1.0f / 1024.0f);
            float var  = (gsumsq[e] - gsum[e] * mean) * (1.0f / 1023.0f);  // ddof=1
            accr += var / (mean * mean + 1e-8f);
        }
        out_lb[0] = 0.01f * accr * 0.125f;
        int off = 0;
        for (int e = 0; e < 8; e++) { offsets[e] = off; lcur[e] = off; off += count[e]; }
    }
    __syncthreads();
    int e = sel[tid];
    int pos = atomicAdd(&lcur[e], 1);
    perm[pos] = tid;
}

// ---------------- gather x -> bf16, bucket order ----------------
__global__ __launch_bounds__(256) void gather_x_kernel(const float* __restrict__ x,
                                                       const int* __restrict__ perm,
                                                       unsigned short* __restrict__ xb)
{
    int slot = blockIdx.x * 4 + (threadIdx.x >> 6);
    int lane = threadIdx.x & 63;
    int t = perm[slot];
    const float4* src = (const float4*)(x + (long)t * Hdim);
    unsigned short* dst = xb + (long)slot * Hdim;
#pragma unroll
    for (int i = 0; i < 3; i++) {
        int c = lane + 64 * i;
        *(short4v*)(dst + c * 4) = pack4(src[c]);
    }
}

// ---------------- GEMM1: hmid = gelu(xb @ w1^T + b1) -> bf16 ----------------
// tile 128(M) x 64(N), BK=128, grid (8, 48, 2); blockIdx.x = expert (XCD affinity)
__global__ __launch_bounds__(256) void gemm1_kernel(
    const unsigned short* __restrict__ xb, const float* __restrict__ w1, const float* __restrict__ b1,
    const int* __restrict__ count, const int* __restrict__ offsets,
    unsigned short* __restrict__ hmid)
{
    int e = blockIdx.x;
    int nloc = count[e];
    int m0 = blockIdx.z << 7;
    if (m0 >= nloc) return;
    int n0 = blockIdx.y << 6;
    int off = offsets[e];

    __shared__ __align__(16) unsigned short As[128 * 128];  // 32 KB, XOR-swizzled
    __shared__ __align__(16) unsigned short Bs[64 * LDB];   // 17.4 KB

    int tid = threadIdx.x;
    int lane = tid & 63, wave = tid >> 6;
    int quad = lane >> 4, l16 = lane & 15;
    int wm = (wave >> 1) << 6, wn = (wave & 1) << 5;        // wave tile 64 x 32

    // A: 2048 16B-chunks per 128x128 tile, 8 per thread
    const unsigned short* aG[8];
    unsigned short* aL[8];
#pragma unroll
    for (int i = 0; i < 8; i++) {
        int p = (wave * 8 + i) * 64 + lane;
        int row = p >> 4;
        int kc = (p & 15) ^ (row & 15);
        int m = m0 + row; int mm = m < nloc ? m : nloc - 1;
        aG[i] = xb + (long)(off + mm) * Hdim + kc * 8;
        aL[i] = (unsigned short*)As + p * 8;
    }
    // B: 64 rows x 128 fp32 per iter
    int kq5 = tid & 31, rb8 = tid >> 5;
    const float* bp[8];
#pragma unroll
    for (int s = 0; s < 8; s++)
        bp[s] = w1 + ((long)e * Idim + n0 + rb8 + 8 * s) * Hdim + kq5 * 4;

    v4f acc[4][2];
#pragma unroll
    for (int i = 0; i < 4; i++)
#pragma unroll
        for (int j = 0; j < 2; j++) acc[i][j] = (v4f){0.f, 0.f, 0.f, 0.f};

    float4 nb[8];
#pragma unroll
    for (int s = 0; s < 8; s++) nb[s] = *(const float4*)bp[s];

    for (int kb = 0; kb < Hdim; kb += 128) {
        __syncthreads();
#pragma unroll
        for (int i = 0; i < 8; i++) gl2lds16(aG[i] + kb, aL[i]);
#pragma unroll
        for (int s = 0; s < 8; s++)
            *(short4v*)(Bs + (rb8 + 8 * s) * LDB + kq5 * 4) = pack4(nb[s]);
        __syncthreads();
        if (kb + 128 < Hdim) {
#pragma unroll
            for (int s = 0; s < 8; s++) nb[s] = *(const float4*)(bp[s] + kb + 128);
        }
#pragma unroll
        for (int s4 = 0; s4 < 4; s4++) {
            short8 af[4], bf2[2];
#pragma unroll
            for (int i = 0; i < 4; i++) {
                int r = wm + i * 16 + l16;
                af[i] = *(const short8*)(As + r * 128 + (((s4 * 4 + quad) ^ (r & 15)) * 8));
            }
#pragma unroll
            for (int j = 0; j < 2; j++)
                bf2[j] = *(const short8*)(Bs + (wn + j * 16 + l16) * LDB + s4 * 32 + quad * 8);
#pragma unroll
            for (int i = 0; i < 4; i++)
#pragma unroll
                for (int j = 0; j < 2; j++)
                    acc[i][j] = __builtin_amdgcn_mfma_f32_16x16x32_bf16(af[i], bf2[j], acc[i][j], 0, 0, 0);
        }
    }

#pragma unroll
    for (int i = 0; i < 4; i++) {
        int mr = wm + i * 16 + quad * 4;
#pragma unroll
        for (int r = 0; r < 4; r++) {
            int m = m0 + mr + r;
            if (m >= nloc) continue;
            long slot = off + m;
#pragma unroll
            for (int j = 0; j < 2; j++) {
                int n = n0 + wn + j * 16 + l16;
                float v = acc[i][j][r] + b1[e * Idim + n];
                float g = 0.5f * v * (1.0f + erff(v * 0.70710678118654752f));
                hmid[slot * Idim + n] = f2bf(g);
            }
        }
    }
}

// ---------------- GEMM2: out[t] += hmid @ w2^T (+b2 at sc==0); split-K=8 ----------------
// tile 128(M) x 64(N), Kc=384, BK=128, grid (8, 96, 2); blockIdx.x = expert
__global__ __launch_bounds__(256) void gemm2_kernel(
    const unsigned short* __restrict__ hmid, const float* __restrict__ w2,
    const float* __restrict__ b2,
    const int* __restrict__ count, const int* __restrict__ offsets,
    const int* __restrict__ perm, float* __restrict__ out)
{
    int e = blockIdx.x;
    int nloc = count[e];
    int m0 = blockIdx.z << 7;
    if (m0 >= nloc) return;
    int y = blockIdx.y;
    int sc = y & 7;                 // split-K chunk
    int n0 = (y >> 3) << 6;         // 12 n-tiles
    long kbase = (long)sc * 384;
    int off = offsets[e];

    __shared__ __align__(16) unsigned short As[128 * 128];  // 32 KB
    __shared__ __align__(16) unsigned short Bs[64 * LDB];   // 17.4 KB

    int tid = threadIdx.x;
    int lane = tid & 63, wave = tid >> 6;
    int quad = lane >> 4, l16 = lane & 15;
    int wm = (wave >> 1) << 6, wn = (wave & 1) << 5;

    const unsigned short* aG[8];
    unsigned short* aL[8];
#pragma unroll
    for (int i = 0; i < 8; i++) {
        int p = (wave * 8 + i) * 64 + lane;
        int row = p >> 4;
        int kc = (p & 15) ^ (row & 15);
        int m = m0 + row; int mm = m < nloc ? m : nloc - 1;
        aG[i] = hmid + (long)(off + mm) * Idim + kbase + kc * 8;
        aL[i] = (unsigned short*)As + p * 8;
    }
    int kq5 = tid & 31, rb8 = tid >> 5;
    const float* bp[8];
#pragma unroll
    for (int s = 0; s < 8; s++)
        bp[s] = w2 + ((long)e * Hdim + n0 + rb8 + 8 * s) * Idim + kbase + kq5 * 4;

    v4f acc[4][2];
#pragma unroll
    for (int i = 0; i < 4; i++)
#pragma unroll
        for (int j = 0; j < 2; j++) acc[i][j] = (v4f){0.f, 0.f, 0.f, 0.f};

    float4 nb[8];
#pragma unroll
    for (int s = 0; s < 8; s++) nb[s] = *(const float4*)bp[s];

    for (int kb = 0; kb < 384; kb += 128) {
        __syncthreads();
#pragma unroll
        for (int i = 0; i < 8; i++) gl2lds16(aG[i] + kb, aL[i]);
#pragma unroll
        for (int s = 0; s < 8; s++)
            *(short4v*)(Bs + (rb8 + 8 * s) * LDB + kq5 * 4) = pack4(nb[s]);
        __syncthreads();
        if (kb + 128 < 384) {
#pragma unroll
            for (int s = 0; s < 8; s++) nb[s] = *(const float4*)(bp[s] + kb + 128);
        }
#pragma unroll
        for (int s4 = 0; s4 < 4; s4++) {
            short8 af[4], bf2[2];
#pragma unroll
            for (int i = 0; i < 4; i++) {
                int r = wm + i * 16 + l16;
                af[i] = *(const short8*)(As + r * 128 + (((s4 * 4 + quad) ^ (r & 15)) * 8));
            }
#pragma unroll
            for (int j = 0; j < 2; j++)
                bf2[j] = *(const short8*)(Bs + (wn + j * 16 + l16) * LDB + s4 * 32 + quad * 8);
#pragma unroll
            for (int i = 0; i < 4; i++)
#pragma unroll
                for (int j = 0; j < 2; j++)
                    acc[i][j] = __builtin_amdgcn_mfma_f32_16x16x32_bf16(af[i], bf2[j], acc[i][j], 0, 0, 0);
        }
    }

#pragma unroll
    for (int i = 0; i < 4; i++) {
        int mr = wm + i * 16 + quad * 4;
#pragma unroll
        for (int r = 0; r < 4; r++) {
            int m = m0 + mr + r;
            if (m >= nloc) continue;
            int t = perm[off + m];
#pragma unroll
            for (int j = 0; j < 2; j++) {
                int n = n0 + wn + j * 16 + l16;
                float v = acc[i][j][r];
                if (sc == 0) v += b2[e * Hdim + n];
                atomicAdd(out + (long)t * Hdim + n, v);
            }
        }
    }
}

extern "C" void kernel_launch(void* const* d_in, const int* in_sizes, int n_in,
                              void* d_out, int out_size, void* d_ws, size_t ws_size,
                              hipStream_t stream)
{
    const float* x  = (const float*)d_in[0];
    const float* gw = (const float*)d_in[1];
    const float* gb = (const float*)d_in[2];
    const float* w1 = (const float*)d_in[3];
    const float* b1 = (const float*)d_in[4];
    const float* w2 = (const float*)d_in[5];
    const float* b2 = (const float*)d_in[6];
    float* out = (float*)d_out;

    float* gsum    = (float*)d_ws;
    float* gsumsq  = gsum + 8;
    int*   count   = (int*)d_ws + 16;
    int*   offsets = (int*)d_ws + 24;
    int*   sel     = (int*)d_ws + 40;
    int*   perm    = (int*)d_ws + 40 + 1024;
    unsigned short* xb   = (unsigned short*)((char*)d_ws + 8704);
    unsigned short* hmid = (unsigned short*)((char*)d_ws + 8704 + (size_t)Tn * Hdim * 2);

    hipMemsetAsync(d_ws, 0, 160, stream);
    hipMemsetAsync(out, 0, (size_t)Tn * Hdim * sizeof(float), stream);
    gate_kernel<<<128, 256, 0, stream>>>(x, gw, gb, gsum, gsumsq, count, sel);
    finscat_kernel<<<1, 1024, 0, stream>>>(gsum, gsumsq, count, offsets, sel, perm,
                                           out + (long)Tn * Hdim);
    gather_x_kernel<<<256, 256, 0, stream>>>(x, perm, xb);
    gemm1_kernel<<<dim3(8, 48, 2), 256, 0, stream>>>(xb, w1, b1, count, offsets, hmid);
    gemm2_kernel<<<dim3(8, 96, 2), 256, 0, stream>>>(hmid, w2, b2, count, offsets, perm, out);
}